// Round 3
// baseline (294.411 us; speedup 1.0000x reference)
//
#include <hip/hip_runtime.h>

#define N_FEAT 784
#define NF4    196          // N_FEAT / 4
#define N_CLS  10

// Folded network: logits = x @ Weff^T + beff; out = softmax(logits).
// Weff/beff recomputed per block into LDS (7840 fused-FMA, inputs L2/L3-hot).
// Main loop: each 16-lane group owns 4 rows; lanes stride the 196 float4
// features; Weff via broadcast ds_read_b128 amortized over 4 rows.
// amdgpu_waves_per_eu(4,4) pins the allocator at the 128-VGPR tier so the
// 40-accumulator live set does not spill (R1 lesson: heuristic targeted 64
// VGPRs and spilled 500 MB of scratch).
__global__ __launch_bounds__(256)
__attribute__((amdgpu_waves_per_eu(4, 4)))
void sparse_fused_kernel(
    const float* __restrict__ x,
    const float* __restrict__ Wsp,   // [784,2]
    const float* __restrict__ bsp,   // [784,2]
    const float* __restrict__ fcw,   // [10,784]
    const float* __restrict__ fcb,   // [10]
    float* __restrict__ out)         // [65536,10]
{
    __shared__ float Wl[N_CLS * N_FEAT];   // folded weights, [10][784]
    __shared__ float bl[N_CLS];            // folded bias
    __shared__ float bred[4][N_CLS];

    const int tid  = threadIdx.x;
    const int lane = tid & 63;
    const int wave = tid >> 6;

    // ---- per-block fold of the sparse layer into fc ----
    float bacc[N_CLS];
#pragma unroll
    for (int n = 0; n < N_CLS; ++n) bacc[n] = 0.f;

    for (int i = tid; i < N_FEAT; i += 256) {
        // scatter map from the reference (incl. the i==782 wraparound bug)
        int c0 = (i == 782) ? 0 : i;
        int c1 = (i == 782) ? 1 : ((i == 783) ? 0 : (i + 1));
        float w0 = Wsp[2 * i], w1 = Wsp[2 * i + 1];
        float b0 = bsp[2 * i], b1 = bsp[2 * i + 1];
#pragma unroll
        for (int n = 0; n < N_CLS; ++n) {
            float f0 = fcw[n * N_FEAT + c0];
            float f1 = fcw[n * N_FEAT + c1];
            Wl[n * N_FEAT + i] = f0 * w0 + f1 * w1;
            bacc[n] += f0 * b0 + f1 * b1;
        }
    }
#pragma unroll
    for (int n = 0; n < N_CLS; ++n) {
#pragma unroll
        for (int d = 1; d < 64; d <<= 1)
            bacc[n] += __shfl_xor(bacc[n], d, 64);
    }
    if (lane == 0) {
#pragma unroll
        for (int n = 0; n < N_CLS; ++n) bred[wave][n] = bacc[n];
    }
    __syncthreads();
    if (tid < N_CLS)
        bl[tid] = bred[0][tid] + bred[1][tid] + bred[2][tid] + bred[3][tid] + fcb[tid];
    __syncthreads();

    // ---- main GEMM + softmax: 16-lane group owns 4 rows, one pass ----
    const float4* Wl4 = (const float4*)Wl;
    const int gw = blockIdx.x * 4 + wave;   // global wave id, 0..4095
    const int g  = lane >> 4;               // 16-lane group, 0..3
    const int sl = lane & 15;

    const int rbase = gw * 16 + g * 4;      // 4096 waves * 16 rows = 65536
    const float4* xr0 = (const float4*)(x + (size_t)(rbase + 0) * N_FEAT);
    const float4* xr1 = (const float4*)(x + (size_t)(rbase + 1) * N_FEAT);
    const float4* xr2 = (const float4*)(x + (size_t)(rbase + 2) * N_FEAT);
    const float4* xr3 = (const float4*)(x + (size_t)(rbase + 3) * N_FEAT);

    float acc[N_CLS][4];
#pragma unroll
    for (int n = 0; n < N_CLS; ++n)
#pragma unroll
        for (int r = 0; r < 4; ++r) acc[n][r] = 0.f;

    // lanes stride the 196 float4 features; 12 full steps + tail (sl<4)
    for (int k4 = sl; k4 < NF4; k4 += 16) {
        float4 x0 = xr0[k4];
        float4 x1 = xr1[k4];
        float4 x2 = xr2[k4];
        float4 x3 = xr3[k4];
#pragma unroll
        for (int n = 0; n < N_CLS; ++n) {
            float4 wv = Wl4[n * NF4 + k4];
            acc[n][0] += wv.x * x0.x + wv.y * x0.y + wv.z * x0.z + wv.w * x0.w;
            acc[n][1] += wv.x * x1.x + wv.y * x1.y + wv.z * x1.z + wv.w * x1.w;
            acc[n][2] += wv.x * x2.x + wv.y * x2.y + wv.z * x2.z + wv.w * x2.w;
            acc[n][3] += wv.x * x3.x + wv.y * x3.y + wv.z * x3.z + wv.w * x3.w;
        }
    }

    // intra-group (16-lane) butterfly; all 4 groups reduce in parallel
#pragma unroll
    for (int d = 1; d < 16; d <<= 1) {
#pragma unroll
        for (int n = 0; n < N_CLS; ++n) {
#pragma unroll
            for (int r = 0; r < 4; ++r)
                acc[n][r] += __shfl_xor(acc[n][r], d, 64);
        }
    }

    // fused softmax for all 4 rows (redundant across the 16 lanes; tiny)
    float m[4] = {-1e30f, -1e30f, -1e30f, -1e30f};
#pragma unroll
    for (int n = 0; n < N_CLS; ++n) {
#pragma unroll
        for (int r = 0; r < 4; ++r) {
            acc[n][r] += bl[n];
            m[r] = fmaxf(m[r], acc[n][r]);
        }
    }
    float den[4] = {0.f, 0.f, 0.f, 0.f};
#pragma unroll
    for (int n = 0; n < N_CLS; ++n) {
#pragma unroll
        for (int r = 0; r < 4; ++r) {
            acc[n][r] = __expf(acc[n][r] - m[r]);
            den[r] += acc[n][r];
        }
    }
#pragma unroll
    for (int r = 0; r < 4; ++r) {
        float inv = 1.0f / den[r];
        float v = acc[0][r];
#pragma unroll
        for (int n = 1; n < N_CLS; ++n) v = (sl == n) ? acc[n][r] : v;
        if (sl < N_CLS)
            out[(size_t)(rbase + r) * N_CLS + sl] = v * inv;
    }
}

extern "C" void kernel_launch(void* const* d_in, const int* in_sizes, int n_in,
                              void* d_out, int out_size, void* d_ws, size_t ws_size,
                              hipStream_t stream) {
    const float* x   = (const float*)d_in[0];   // [65536,784]
    const float* Wsp = (const float*)d_in[1];   // [784,2]
    const float* bsp = (const float*)d_in[2];   // [784,2]
    const float* fcw = (const float*)d_in[3];   // [10,784]
    const float* fcb = (const float*)d_in[4];   // [10]
    float* out = (float*)d_out;                 // [65536,10]

    // 1024 blocks x 256 threads: 4 waves/block, 16 rows/wave
    sparse_fused_kernel<<<1024, 256, 0, stream>>>(x, Wsp, bsp, fcw, fcb, out);
}